// Round 12
// baseline (143.367 us; speedup 1.0000x reference)
//
#include <hip/hip_runtime.h>
#include <hip/hip_fp16.h>

typedef _Float16 f16x8 __attribute__((ext_vector_type(8)));
typedef _Float16 f16x4 __attribute__((ext_vector_type(4)));
typedef float    f32x4 __attribute__((ext_vector_type(4)));

#define LOG2E 1.44269504f

// ---------------------------------------------------------------------------
// Staging: 128 rows x 64 halves fp16 tile -> 16 KB linear LDS via
// global_load_lds dwordx4 (4 vmem instrs/thread). Source col pre-swizzled
// (byte ^= (row&7)<<4); readers apply the same XOR (rule #21).
// ---------------------------------------------------------------------------
__device__ __forceinline__ void stage128x64(const _Float16* __restrict__ g, int ld,
                                            void* lds, int tid)
{
    const int r0   = tid >> 3;
    const int colh = ((tid & 7) ^ (r0 & 7)) << 3;
    char* lbase = (char*)lds + (tid >> 6) * 1024;
#pragma unroll
    for (int i = 0; i < 4; i++) {
        const _Float16* src = g + (size_t)(i * 32 + r0) * ld + colh;
        __builtin_amdgcn_global_load_lds(
            (const __attribute__((address_space(1))) void*)src,
            (__attribute__((address_space(3))) void*)(lbase + i * 4096),
            16, 0, 0);
    }
}

__device__ __forceinline__ f16x8 lds_frag(const void* lds, int row, int colh)
{
    const int off = row * 128 + ((colh * 2) ^ ((row & 7) << 4));
    return *(const f16x8*)((const char*)lds + off);
}

// ---------------------------------------------------------------------------
// Counted-vmcnt depth-2 pipelined GEMM loop (T4) — the R8 schedule (best).
// ---------------------------------------------------------------------------
template<int NK>
__device__ __forceinline__ void gemm_loop_cv(const _Float16* __restrict__ A, int lda,
                                             const _Float16* __restrict__ B, int ldb,
                                             _Float16* a0, _Float16* a1,
                                             _Float16* b0, _Float16* b1,
                                             f32x4 acc[4][4], int tid,
                                             int wr, int wc, int lrow, int lkg)
{
    stage128x64(A, lda, a0, tid);
    stage128x64(B, ldb, b0, tid);
    stage128x64(A + 64, lda, a1, tid);
    stage128x64(B + 64, ldb, b1, tid);
    asm volatile("s_waitcnt vmcnt(8)" ::: "memory");   // tile0 landed
    __builtin_amdgcn_s_barrier();
    __builtin_amdgcn_sched_barrier(0);

    for (int t = 0; t < NK; ++t) {
        _Float16* acur = (t & 1) ? a1 : a0;
        _Float16* bcur = (t & 1) ? b1 : b0;

        f16x8 af[2][4], bf[2][4];
#pragma unroll
        for (int kk = 0; kk < 2; kk++) {
#pragma unroll
            for (int mi = 0; mi < 4; mi++)
                af[kk][mi] = lds_frag(acur, wr * 64 + mi * 16 + lrow, kk * 32 + lkg * 8);
#pragma unroll
            for (int ni = 0; ni < 4; ni++)
                bf[kk][ni] = lds_frag(bcur, wc * 64 + ni * 16 + lrow, kk * 32 + lkg * 8);
        }
        asm volatile("s_waitcnt lgkmcnt(0)" ::: "memory");
        __builtin_amdgcn_sched_barrier(0);
        __builtin_amdgcn_s_barrier();

        if (t + 2 < NK) {
            stage128x64(A + (size_t)(t + 2) * 64, lda, acur, tid);
            stage128x64(B + (size_t)(t + 2) * 64, ldb, bcur, tid);
        }
        __builtin_amdgcn_sched_barrier(0);

        __builtin_amdgcn_s_setprio(1);
#pragma unroll
        for (int kk = 0; kk < 2; kk++)
#pragma unroll
            for (int mi = 0; mi < 4; mi++)
#pragma unroll
                for (int ni = 0; ni < 4; ni++)
                    acc[mi][ni] = __builtin_amdgcn_mfma_f32_16x16x32_f16(
                        af[kk][mi], bf[kk][ni], acc[mi][ni], 0, 0, 0);
        __builtin_amdgcn_s_setprio(0);

        if (t + 2 < NK) asm volatile("s_waitcnt vmcnt(8)" ::: "memory");
        else            asm volatile("s_waitcnt vmcnt(0)" ::: "memory");
        __builtin_amdgcn_sched_barrier(0);
        __builtin_amdgcn_s_barrier();
        __builtin_amdgcn_sched_barrier(0);
    }
}

// ---------------------------------------------------------------------------
// Kernel 0: convert x -> fp16 xh; W{q,k,v} -> fp16 transposed Wt[3][n][k].
// ---------------------------------------------------------------------------
__global__ __launch_bounds__(256)
void convert_kernel(const float* __restrict__ x,
                    const float* __restrict__ Wq,
                    const float* __restrict__ Wk,
                    const float* __restrict__ Wv,
                    _Float16* __restrict__ xh,
                    _Float16* __restrict__ Wt)
{
    const int b = blockIdx.x;
    if (b < 2048) {
        const size_t base = (size_t)b * 4096 + (size_t)threadIdx.x * 4;
#pragma unroll
        for (int i = 0; i < 4; i++) {
            f32x4 v = *(const f32x4*)(x + base + i * 1024);
            f16x4 h;
#pragma unroll
            for (int j = 0; j < 4; j++) h[j] = (_Float16)v[j];
            *(f16x4*)(xh + base + i * 1024) = h;
        }
    } else {
        __shared__ float tb[32][33];
        const int t = b - 2048;
        const int mat = t >> 8;
        const int tile = t & 255;
        const int tr = tile >> 4, tc = tile & 15;
        const float* W = (mat == 0) ? Wq : (mat == 1) ? Wk : Wv;
        const int r = threadIdx.x >> 5, c = threadIdx.x & 31;
#pragma unroll
        for (int p = 0; p < 4; p++)
            tb[p * 8 + r][c] = W[(size_t)(tr * 32 + p * 8 + r) * 512 + tc * 32 + c];
        __syncthreads();
#pragma unroll
        for (int p = 0; p < 4; p++)
            Wt[((size_t)mat * 512 + tc * 32 + p * 8 + r) * 512 + tr * 32 + c] =
                (_Float16)tb[c][p * 8 + r];
    }
}

// ---------------------------------------------------------------------------
// Kernel 1: QKV projection (all-fp16). Q,K row-major; V transposed [b][d][m].
// grid (mb=128 x, cb=12 y) for XCD-shared xh panels.
// ---------------------------------------------------------------------------
__global__ __launch_bounds__(256, 2)
void proj_kernel(const _Float16* __restrict__ xh,
                 const _Float16* __restrict__ Wt,
                 _Float16* __restrict__ Qf,
                 _Float16* __restrict__ Kf,
                 _Float16* __restrict__ Vt)
{
    __shared__ _Float16 a0[128 * 64], a1[128 * 64];
    __shared__ _Float16 b0[128 * 64], b1[128 * 64];

    const int tid = threadIdx.x;
    const int mb = blockIdx.x, cb = blockIdx.y;
    const int mat = cb >> 2, nb = cb & 3;
    const int m0 = mb * 128, n0 = nb * 128;

    const _Float16* Abase = xh + (size_t)m0 * 512;
    const _Float16* Bbase = Wt + ((size_t)mat * 512 + n0) * 512;

    const int lane = tid & 63;
    const int w = tid >> 6;
    const int wr = w >> 1, wc = w & 1;
    const int lrow = lane & 15, lkg = lane >> 4;

    f32x4 acc[4][4];
#pragma unroll
    for (int i = 0; i < 4; i++)
#pragma unroll
        for (int j = 0; j < 4; j++) acc[i][j] = (f32x4)0.0f;

    gemm_loop_cv<8>(Abase, 512, Bbase, 512, a0, a1, b0, b1,
                    acc, tid, wr, wc, lrow, lkg);

    if (mat < 2) {
        _Float16* Out = (mat == 0) ? Qf : Kf;
#pragma unroll
        for (int mi = 0; mi < 4; mi++) {
            const int mbase = m0 + wr * 64 + mi * 16 + lkg * 4;
#pragma unroll
            for (int ni = 0; ni < 4; ni++) {
                const int ncol = n0 + wc * 64 + ni * 16 + lrow;
#pragma unroll
                for (int r = 0; r < 4; r++)
                    Out[(size_t)(mbase + r) * 512 + ncol] = (_Float16)acc[mi][ni][r];
            }
        }
    } else {
#pragma unroll
        for (int mi = 0; mi < 4; mi++) {
            const int mglob = m0 + wr * 64 + mi * 16 + lkg * 4;
            const int b = mglob >> 11, mloc = mglob & 2047;
#pragma unroll
            for (int ni = 0; ni < 4; ni++) {
                const int d = n0 + wc * 64 + ni * 16 + lrow;
                f16x4 h;
#pragma unroll
                for (int r = 0; r < 4; r++) h[r] = (_Float16)acc[mi][ni][r];
                *(f16x4*)&Vt[((size_t)b * 512 + d) * 2048 + mloc] = h;
            }
        }
    }
}

// ---------------------------------------------------------------------------
// Kernel 2: S-tile via SWAPPED operands (A=K, B=Q -> per-lane q-rows).
// C/D mapping (verified): key = wr*64+mi*16+lkg*4+rr, q = wc*64+ni*16+lrow.
// Row-softmax stats: 15 local fmax + 2 shfl_xor (lkg butterfly) + 1-KB LDS
// exchange between wr-wave-pair (2 barriers). P stored from registers.
// Same P/ML contracts as before. grid (mb=ktile 16, nb=qtile 16, chunk).
// ---------------------------------------------------------------------------
__global__ __launch_bounds__(256, 2)
void score_kernel(const _Float16* __restrict__ Qf,
                  const _Float16* __restrict__ Kf,
                  _Float16* __restrict__ P,
                  float2* __restrict__ ML, int b0)
{
    __shared__ __align__(16) char smem[65536];
    _Float16* a0  = (_Float16*)smem;
    _Float16* a1  = (_Float16*)(smem + 16384);
    _Float16* b0p = (_Float16*)(smem + 32768);
    _Float16* b1p = (_Float16*)(smem + 49152);
    // tiny reduce buffers alias slot space (dead after loop's final barrier)
    float (*redm)[128] = (float(*)[128])smem;           // 1 KB
    float (*reds)[128] = (float(*)[128])(smem + 1024);  // 1 KB

    const int tid = threadIdx.x;
    const int mb = blockIdx.x, nb = blockIdx.y, bl = blockIdx.z;
    const int bg = b0 + bl;

    // SWAP: A = K-tile (keys), B = Q-tile (q-rows)
    const _Float16* Abase = Kf + (size_t)(bg * 2048 + mb * 128) * 512;
    const _Float16* Bbase = Qf + (size_t)(bg * 2048 + nb * 128) * 512;

    const int lane = tid & 63;
    const int w = tid >> 6;
    const int wr = w >> 1, wc = w & 1;
    const int lrow = lane & 15, lkg = lane >> 4;

    f32x4 acc[4][4];
#pragma unroll
    for (int i = 0; i < 4; i++)
#pragma unroll
        for (int j = 0; j < 4; j++) acc[i][j] = (f32x4)0.0f;

    gemm_loop_cv<8>(Abase, 512, Bbase, 512, a0, a1, b0p, b1p,
                    acc, tid, wr, wc, lrow, lkg);
    // loop ends with vmcnt(0)+barrier: slots dead -> redm/reds reuse safe

    _Float16* Pb = P + (size_t)bl * 2048 * 2048;

    // ---- per-lane q-rows: 4 q's (ni), 16 keys each (mi,rr) ----
    float mt[4], lt[4];
#pragma unroll
    for (int ni = 0; ni < 4; ni++) {
        float m = acc[0][ni][0];
#pragma unroll
        for (int mi = 0; mi < 4; mi++)
#pragma unroll
            for (int rr = 0; rr < 4; rr++) m = fmaxf(m, acc[mi][ni][rr]);
        m = fmaxf(m, __shfl_xor(m, 16));
        m = fmaxf(m, __shfl_xor(m, 32));
        mt[ni] = m;
    }
    if (lkg == 0) {
#pragma unroll
        for (int ni = 0; ni < 4; ni++)
            redm[wr][wc * 64 + ni * 16 + lrow] = mt[ni];
    }
    __syncthreads();
#pragma unroll
    for (int ni = 0; ni < 4; ni++)
        mt[ni] = fmaxf(mt[ni], redm[wr ^ 1][wc * 64 + ni * 16 + lrow]);

#pragma unroll
    for (int ni = 0; ni < 4; ni++) {
        float l = 0.0f;
#pragma unroll
        for (int mi = 0; mi < 4; mi++)
#pragma unroll
            for (int rr = 0; rr < 4; rr++) {
                float e = exp2f((acc[mi][ni][rr] - mt[ni]) * LOG2E);
                acc[mi][ni][rr] = e;
                l += e;
            }
        l += __shfl_xor(l, 16);
        l += __shfl_xor(l, 32);
        lt[ni] = l;
    }
    if (lkg == 0) {
#pragma unroll
        for (int ni = 0; ni < 4; ni++)
            reds[wr][wc * 64 + ni * 16 + lrow] = lt[ni];
    }
    __syncthreads();
#pragma unroll
    for (int ni = 0; ni < 4; ni++)
        lt[ni] += reds[wr ^ 1][wc * 64 + ni * 16 + lrow];

    if (wr == 0 && lkg == 0) {
#pragma unroll
        for (int ni = 0; ni < 4; ni++) {
            const int q = nb * 128 + wc * 64 + ni * 16 + lrow;
            float2 v; v.x = mt[ni]; v.y = lt[ni];
            ML[((size_t)bl * 2048 + q) * 16 + mb] = v;
        }
    }

    // ---- P stores straight from registers: f16x4 per (ni,mi) ----
#pragma unroll
    for (int ni = 0; ni < 4; ni++) {
        const int q = nb * 128 + wc * 64 + ni * 16 + lrow;
        _Float16* prow = Pb + (size_t)q * 2048 + mb * 128 + wr * 64 + lkg * 4;
#pragma unroll
        for (int mi = 0; mi < 4; mi++) {
            f16x4 h;
#pragma unroll
            for (int rr = 0; rr < 4; rr++) h[rr] = (_Float16)acc[mi][ni][rr];
            *(f16x4*)&prow[mi * 16] = h;
        }
    }
}

// ---------------------------------------------------------------------------
// Kernel 4: out = scaled-P @ V, R8 counted-vmcnt loop with per-ktile scale
// on the A fragments. grid.x=64 (db=x>>4, nb=x&15 for XCD-shared P panels).
// Output fp32 [b][2048][512].
// ---------------------------------------------------------------------------
__global__ __launch_bounds__(256, 2)
void out_kernel(const _Float16* __restrict__ P,
                const _Float16* __restrict__ Vt,
                const float2* __restrict__ ML,
                float* __restrict__ out, int b0)
{
    __shared__ _Float16 a0[128 * 64], a1[128 * 64];
    __shared__ _Float16 b0p[128 * 64], b1p[128 * 64];
    __shared__ float scale_lds[128][17];

    const int tid = threadIdx.x;
    const int db = blockIdx.x >> 4, nb = blockIdx.x & 15, bl = blockIdx.y;
    const int bg = b0 + bl;

    if (tid < 128) {
        const float2* mlrow = ML + ((size_t)bl * 2048 + nb * 128 + tid) * 16;
        float2 ml[16];
        float M = -3.4e38f;
#pragma unroll
        for (int t = 0; t < 16; t++) { ml[t] = mlrow[t]; M = fmaxf(M, ml[t].x); }
        float L = 0.0f;
#pragma unroll
        for (int t = 0; t < 16; t++) L += ml[t].y * exp2f((ml[t].x - M) * LOG2E);
        const float invL = 1.0f / L;
#pragma unroll
        for (int t = 0; t < 16; t++)
            scale_lds[tid][t] = exp2f((ml[t].x - M) * LOG2E) * invL;
    }

    const _Float16* Abase = P  + (size_t)bl * 2048 * 2048 + (size_t)(nb * 128) * 2048;
    const _Float16* Bbase = Vt + (size_t)bg * 512  * 2048 + (size_t)(db * 128) * 2048;

    const int lane = tid & 63;
    const int w = tid >> 6;
    const int wr = w >> 1, wc = w & 1;
    const int lrow = lane & 15, lkg = lane >> 4;

    f32x4 acc[4][4];
#pragma unroll
    for (int i = 0; i < 4; i++)
#pragma unroll
        for (int j = 0; j < 4; j++) acc[i][j] = (f32x4)0.0f;

    __syncthreads();   // scale_lds ready; drains ML loads

    // pipeline prologue
    stage128x64(Abase,      2048, a0,  tid);
    stage128x64(Bbase,      2048, b0p, tid);
    stage128x64(Abase + 64, 2048, a1,  tid);
    stage128x64(Bbase + 64, 2048, b1p, tid);
    asm volatile("s_waitcnt vmcnt(8)" ::: "memory");
    __builtin_amdgcn_s_barrier();
    __builtin_amdgcn_sched_barrier(0);

    for (int t = 0; t < 32; ++t) {
        _Float16* acur = (t & 1) ? a1 : a0;
        _Float16* bcur = (t & 1) ? b1p : b0p;
        const int kt = t >> 1;

        f16x8 af[2][4], bf[2][4];
        float sc[4];
#pragma unroll
        for (int kk = 0; kk < 2; kk++) {
#pragma unroll
            for (int mi = 0; mi < 4; mi++)
                af[kk][mi] = lds_frag(acur, wr * 64 + mi * 16 + lrow, kk * 32 + lkg * 8);
#pragma unroll
            for (int ni = 0; ni < 4; ni++)
                bf[kk][ni] = lds_frag(bcur, wc * 64 + ni * 16 + lrow, kk * 32 + lkg * 8);
        }
#pragma unroll
        for (int mi = 0; mi < 4; mi++)
            sc[mi] = scale_lds[wr * 64 + mi * 16 + lrow][kt];
        asm volatile("s_waitcnt lgkmcnt(0)" ::: "memory");
        __builtin_amdgcn_sched_barrier(0);
        __builtin_amdgcn_s_barrier();

        if (t + 2 < 32) {
            stage128x64(Abase + (size_t)(t + 2) * 64, 2048, acur, tid);
            stage128x64(Bbase + (size_t)(t + 2) * 64, 2048, bcur, tid);
        }
        __builtin_amdgcn_sched_barrier(0);

        __builtin_amdgcn_s_setprio(1);
#pragma unroll
        for (int kk = 0; kk < 2; kk++)
#pragma unroll
            for (int mi = 0; mi < 4; mi++) {
                const f16x8 a = af[kk][mi] * (_Float16)sc[mi];
#pragma unroll
                for (int ni = 0; ni < 4; ni++)
                    acc[mi][ni] = __builtin_amdgcn_mfma_f32_16x16x32_f16(
                        a, bf[kk][ni], acc[mi][ni], 0, 0, 0);
            }
        __builtin_amdgcn_s_setprio(0);

        if (t + 2 < 32) asm volatile("s_waitcnt vmcnt(8)" ::: "memory");
        else            asm volatile("s_waitcnt vmcnt(0)" ::: "memory");
        __builtin_amdgcn_sched_barrier(0);
        __builtin_amdgcn_s_barrier();
        __builtin_amdgcn_sched_barrier(0);
    }

#pragma unroll
    for (int mi = 0; mi < 4; mi++) {
        const int nbase = nb * 128 + wr * 64 + mi * 16 + lkg * 4;
#pragma unroll
        for (int ni = 0; ni < 4; ni++) {
            const int d = db * 128 + wc * 64 + ni * 16 + lrow;
#pragma unroll
            for (int rr = 0; rr < 4; rr++)
                out[((size_t)bg * 2048 + nbase + rr) * 512 + d] = acc[mi][ni][rr];
        }
    }
}

// ---------------------------------------------------------------------------
extern "C" void kernel_launch(void* const* d_in, const int* in_sizes, int n_in,
                              void* d_out, int out_size, void* d_ws, size_t ws_size,
                              hipStream_t stream) {
    const float* x  = (const float*)d_in[0];
    const float* Wq = (const float*)d_in[1];
    const float* Wk = (const float*)d_in[2];
    const float* Wv = (const float*)d_in[3];

    const size_t MB = 1024ull * 1024ull;
    char* ws = (char*)d_ws;
    _Float16* Qf = (_Float16*)ws;                                  // 16 MB
    _Float16* Kf = Qf + (size_t)16384 * 512;                       // 16 MB
    _Float16* Vt = Kf + (size_t)16384 * 512;                       // 16 MB
    _Float16* P  = Vt + (size_t)16384 * 512;                       // chunk * 8 MB
    float*    out = (float*)d_out;

    int chunk;
    if      (ws_size >= 120 * MB) chunk = 8;
    else if (ws_size >= 88  * MB) chunk = 4;
    else if (ws_size >= 70  * MB) chunk = 2;
    else                          chunk = 1;

    float2* ML = (float2*)(P + (size_t)chunk * 2048 * 2048);       // chunk * 256 KB

    // Aliases into the P/ML region (dead until score_kernel runs):
    _Float16* xh = (_Float16*)P;                    // 16 MB
    _Float16* Wt = xh + (size_t)16384 * 512;        // 1.5 MB

    convert_kernel<<<2816, 256, 0, stream>>>(x, Wq, Wk, Wv, xh, Wt);
    proj_kernel<<<dim3(128, 12), 256, 0, stream>>>(xh, Wt, Qf, Kf, Vt);

    for (int b0 = 0; b0 < 8; b0 += chunk) {
        score_kernel<<<dim3(16, 16, chunk), 256, 0, stream>>>(Qf, Kf, P, ML, b0);
        out_kernel<<<dim3(64, chunk), 256, 0, stream>>>(P, Vt, ML, out, b0);
    }
}

// Round 13
// 134.187 us; speedup vs baseline: 1.0684x; 1.0684x over previous
//
#include <hip/hip_runtime.h>
#include <hip/hip_fp16.h>

typedef _Float16 f16x8 __attribute__((ext_vector_type(8)));
typedef _Float16 f16x4 __attribute__((ext_vector_type(4)));
typedef float    f32x4 __attribute__((ext_vector_type(4)));

#define LOG2E 1.44269504f

// ---------------------------------------------------------------------------
// Staging: 128 rows x 64 halves fp16 tile -> 16 KB linear LDS via
// global_load_lds dwordx4 (4 vmem instrs/thread). Source col pre-swizzled
// (byte ^= (row&7)<<4); readers apply the same XOR (rule #21).
// ---------------------------------------------------------------------------
__device__ __forceinline__ void stage128x64(const _Float16* __restrict__ g, int ld,
                                            void* lds, int tid)
{
    const int r0   = tid >> 3;
    const int colh = ((tid & 7) ^ (r0 & 7)) << 3;
    char* lbase = (char*)lds + (tid >> 6) * 1024;
#pragma unroll
    for (int i = 0; i < 4; i++) {
        const _Float16* src = g + (size_t)(i * 32 + r0) * ld + colh;
        __builtin_amdgcn_global_load_lds(
            (const __attribute__((address_space(1))) void*)src,
            (__attribute__((address_space(3))) void*)(lbase + i * 4096),
            16, 0, 0);
    }
}

__device__ __forceinline__ f16x8 lds_frag(const void* lds, int row, int colh)
{
    const int off = row * 128 + ((colh * 2) ^ ((row & 7) << 4));
    return *(const f16x8*)((const char*)lds + off);
}

// ---------------------------------------------------------------------------
// Counted-vmcnt depth-2 pipelined GEMM loop (T4) — the R8 schedule (best).
// ---------------------------------------------------------------------------
template<int NK>
__device__ __forceinline__ void gemm_loop_cv(const _Float16* __restrict__ A, int lda,
                                             const _Float16* __restrict__ B, int ldb,
                                             _Float16* a0, _Float16* a1,
                                             _Float16* b0, _Float16* b1,
                                             f32x4 acc[4][4], int tid,
                                             int wr, int wc, int lrow, int lkg)
{
    stage128x64(A, lda, a0, tid);
    stage128x64(B, ldb, b0, tid);
    stage128x64(A + 64, lda, a1, tid);
    stage128x64(B + 64, ldb, b1, tid);
    asm volatile("s_waitcnt vmcnt(8)" ::: "memory");   // tile0 landed
    __builtin_amdgcn_s_barrier();
    __builtin_amdgcn_sched_barrier(0);

    for (int t = 0; t < NK; ++t) {
        _Float16* acur = (t & 1) ? a1 : a0;
        _Float16* bcur = (t & 1) ? b1 : b0;

        f16x8 af[2][4], bf[2][4];
#pragma unroll
        for (int kk = 0; kk < 2; kk++) {
#pragma unroll
            for (int mi = 0; mi < 4; mi++)
                af[kk][mi] = lds_frag(acur, wr * 64 + mi * 16 + lrow, kk * 32 + lkg * 8);
#pragma unroll
            for (int ni = 0; ni < 4; ni++)
                bf[kk][ni] = lds_frag(bcur, wc * 64 + ni * 16 + lrow, kk * 32 + lkg * 8);
        }
        asm volatile("s_waitcnt lgkmcnt(0)" ::: "memory");
        __builtin_amdgcn_sched_barrier(0);
        __builtin_amdgcn_s_barrier();

        if (t + 2 < NK) {
            stage128x64(A + (size_t)(t + 2) * 64, lda, acur, tid);
            stage128x64(B + (size_t)(t + 2) * 64, ldb, bcur, tid);
        }
        __builtin_amdgcn_sched_barrier(0);

        __builtin_amdgcn_s_setprio(1);
#pragma unroll
        for (int kk = 0; kk < 2; kk++)
#pragma unroll
            for (int mi = 0; mi < 4; mi++)
#pragma unroll
                for (int ni = 0; ni < 4; ni++)
                    acc[mi][ni] = __builtin_amdgcn_mfma_f32_16x16x32_f16(
                        af[kk][mi], bf[kk][ni], acc[mi][ni], 0, 0, 0);
        __builtin_amdgcn_s_setprio(0);

        if (t + 2 < NK) asm volatile("s_waitcnt vmcnt(8)" ::: "memory");
        else            asm volatile("s_waitcnt vmcnt(0)" ::: "memory");
        __builtin_amdgcn_sched_barrier(0);
        __builtin_amdgcn_s_barrier();
        __builtin_amdgcn_sched_barrier(0);
    }
}

// ---------------------------------------------------------------------------
// Kernel 0: convert x -> fp16 xh; W{q,k,v} -> fp16 transposed Wt[3][n][k].
// ---------------------------------------------------------------------------
__global__ __launch_bounds__(256)
void convert_kernel(const float* __restrict__ x,
                    const float* __restrict__ Wq,
                    const float* __restrict__ Wk,
                    const float* __restrict__ Wv,
                    _Float16* __restrict__ xh,
                    _Float16* __restrict__ Wt)
{
    const int b = blockIdx.x;
    if (b < 2048) {
        const size_t base = (size_t)b * 4096 + (size_t)threadIdx.x * 4;
#pragma unroll
        for (int i = 0; i < 4; i++) {
            f32x4 v = *(const f32x4*)(x + base + i * 1024);
            f16x4 h;
#pragma unroll
            for (int j = 0; j < 4; j++) h[j] = (_Float16)v[j];
            *(f16x4*)(xh + base + i * 1024) = h;
        }
    } else {
        __shared__ float tb[32][33];
        const int t = b - 2048;
        const int mat = t >> 8;
        const int tile = t & 255;
        const int tr = tile >> 4, tc = tile & 15;
        const float* W = (mat == 0) ? Wq : (mat == 1) ? Wk : Wv;
        const int r = threadIdx.x >> 5, c = threadIdx.x & 31;
#pragma unroll
        for (int p = 0; p < 4; p++)
            tb[p * 8 + r][c] = W[(size_t)(tr * 32 + p * 8 + r) * 512 + tc * 32 + c];
        __syncthreads();
#pragma unroll
        for (int p = 0; p < 4; p++)
            Wt[((size_t)mat * 512 + tc * 32 + p * 8 + r) * 512 + tr * 32 + c] =
                (_Float16)tb[c][p * 8 + r];
    }
}

// ---------------------------------------------------------------------------
// Kernel 1: QKV projection (all-fp16). Q,K row-major; V transposed [b][d][m].
// grid (mb=128 x, cb=12 y) for XCD-shared xh panels.
// ---------------------------------------------------------------------------
__global__ __launch_bounds__(256, 2)
void proj_kernel(const _Float16* __restrict__ xh,
                 const _Float16* __restrict__ Wt,
                 _Float16* __restrict__ Qf,
                 _Float16* __restrict__ Kf,
                 _Float16* __restrict__ Vt)
{
    __shared__ _Float16 a0[128 * 64], a1[128 * 64];
    __shared__ _Float16 b0[128 * 64], b1[128 * 64];

    const int tid = threadIdx.x;
    const int mb = blockIdx.x, cb = blockIdx.y;
    const int mat = cb >> 2, nb = cb & 3;
    const int m0 = mb * 128, n0 = nb * 128;

    const _Float16* Abase = xh + (size_t)m0 * 512;
    const _Float16* Bbase = Wt + ((size_t)mat * 512 + n0) * 512;

    const int lane = tid & 63;
    const int w = tid >> 6;
    const int wr = w >> 1, wc = w & 1;
    const int lrow = lane & 15, lkg = lane >> 4;

    f32x4 acc[4][4];
#pragma unroll
    for (int i = 0; i < 4; i++)
#pragma unroll
        for (int j = 0; j < 4; j++) acc[i][j] = (f32x4)0.0f;

    gemm_loop_cv<8>(Abase, 512, Bbase, 512, a0, a1, b0, b1,
                    acc, tid, wr, wc, lrow, lkg);

    if (mat < 2) {
        _Float16* Out = (mat == 0) ? Qf : Kf;
#pragma unroll
        for (int mi = 0; mi < 4; mi++) {
            const int mbase = m0 + wr * 64 + mi * 16 + lkg * 4;
#pragma unroll
            for (int ni = 0; ni < 4; ni++) {
                const int ncol = n0 + wc * 64 + ni * 16 + lrow;
#pragma unroll
                for (int r = 0; r < 4; r++)
                    Out[(size_t)(mbase + r) * 512 + ncol] = (_Float16)acc[mi][ni][r];
            }
        }
    } else {
#pragma unroll
        for (int mi = 0; mi < 4; mi++) {
            const int mglob = m0 + wr * 64 + mi * 16 + lkg * 4;
            const int b = mglob >> 11, mloc = mglob & 2047;
#pragma unroll
            for (int ni = 0; ni < 4; ni++) {
                const int d = n0 + wc * 64 + ni * 16 + lrow;
                f16x4 h;
#pragma unroll
                for (int r = 0; r < 4; r++) h[r] = (_Float16)acc[mi][ni][r];
                *(f16x4*)&Vt[((size_t)b * 512 + d) * 2048 + mloc] = h;
            }
        }
    }
}

// ---------------------------------------------------------------------------
// Kernel 2: S-tile = Q @ K^T (R8 counted-vmcnt loop), LDS-transpose softmax
// epilogue with SEGMENTED column ownership (R11 best epilogue). Grid is
// BATCH-MAJOR: bl=blockIdx.x so linear id mod 8 == bl -> each XCD owns one
// batch; per-XCD working set (Q+K of one batch) = 4 MB ~= L2 capacity.
// ---------------------------------------------------------------------------
__global__ __launch_bounds__(256, 2)
void score_kernel(const _Float16* __restrict__ Qf,
                  const _Float16* __restrict__ Kf,
                  _Float16* __restrict__ P,
                  float2* __restrict__ ML, int b0)
{
    __shared__ __align__(16) char smem[65536];
    _Float16* a0  = (_Float16*)smem;
    _Float16* a1  = (_Float16*)(smem + 16384);
    _Float16* b0p = (_Float16*)(smem + 32768);
    _Float16* b1p = (_Float16*)(smem + 49152);
    float (*S_lds)[132] = (float(*)[132])smem;     // 33792 B, aliases buffers

    const int tid = threadIdx.x;
    const int bl = blockIdx.x, mb = blockIdx.y, nb = blockIdx.z;
    const int bg = b0 + bl;

    const _Float16* Abase = Qf + (size_t)(bg * 2048 + nb * 128) * 512;
    const _Float16* Bbase = Kf + (size_t)(bg * 2048 + mb * 128) * 512;

    const int lane = tid & 63;
    const int w = tid >> 6;
    const int wr = w >> 1, wc = w & 1;
    const int lrow = lane & 15, lkg = lane >> 4;

    f32x4 acc[4][4];
#pragma unroll
    for (int i = 0; i < 4; i++)
#pragma unroll
        for (int j = 0; j < 4; j++) acc[i][j] = (f32x4)0.0f;

    gemm_loop_cv<8>(Abase, 512, Bbase, 512, a0, a1, b0p, b1p,
                    acc, tid, wr, wc, lrow, lkg);
    // final s_barrier: all waves' frags in regs -> S_lds reuse safe

    _Float16* Pb = P + (size_t)bl * 2048 * 2048;
    const int s  = tid >> 2;          // 0..63: S_lds row this thread reduces
    const int q4 = tid & 3;           // 8-col segment selector

#pragma unroll
    for (int hp = 0; hp < 2; hp++) {
        // ---- scatter this half's acc quadrants into S_lds ----
#pragma unroll
        for (int m2 = 0; m2 < 2; m2++) {
            const int mi = hp * 2 + m2;
            const int srow = wr * 32 + m2 * 16 + lkg * 4;
#pragma unroll
            for (int ni = 0; ni < 4; ni++) {
                const int col = wc * 64 + ni * 16 + lrow;
#pragma unroll
                for (int rr = 0; rr < 4; rr++)
                    S_lds[srow + rr][col] = acc[mi][ni][rr];
            }
        }
        __syncthreads();

        // ---- segmented re-read: thread owns 4 x 8-col runs at 32 stride ----
        f32x4 vv[8];
#pragma unroll
        for (int seg = 0; seg < 4; seg++) {
            vv[seg * 2 + 0] = *(const f32x4*)&S_lds[s][q4 * 8 + seg * 32 + 0];
            vv[seg * 2 + 1] = *(const f32x4*)&S_lds[s][q4 * 8 + seg * 32 + 4];
        }

        float m = vv[0][0];
#pragma unroll
        for (int j = 0; j < 8; j++)
#pragma unroll
            for (int jj = 0; jj < 4; jj++) m = fmaxf(m, vv[j][jj]);
        m = fmaxf(m, __shfl_xor(m, 1));
        m = fmaxf(m, __shfl_xor(m, 2));

        float l = 0.0f;
#pragma unroll
        for (int j = 0; j < 8; j++)
#pragma unroll
            for (int jj = 0; jj < 4; jj++) {
                float e = exp2f((vv[j][jj] - m) * LOG2E);
                vv[j][jj] = e;
                l += e;
            }
        l += __shfl_xor(l, 1);
        l += __shfl_xor(l, 2);

        const int q_local = (s >> 5) * 64 + hp * 32 + (s & 31);
        const int q = nb * 128 + q_local;

        if (q4 == 0) {
            float2 v; v.x = m; v.y = l;
            ML[((size_t)bl * 2048 + q) * 16 + mb] = v;
        }

        // ---- pack fp16: per seg, lanes 0-3 write dense 64 B ----
#pragma unroll
        for (int seg = 0; seg < 4; seg++) {
            f16x8 h;
#pragma unroll
            for (int jj = 0; jj < 4; jj++) {
                h[jj]     = (_Float16)vv[seg * 2 + 0][jj];
                h[jj + 4] = (_Float16)vv[seg * 2 + 1][jj];
            }
            *(f16x8*)&Pb[(size_t)q * 2048 + mb * 128 + q4 * 8 + seg * 32] = h;
        }
        __syncthreads();   // S_lds reads done before next half overwrites
    }
}

// ---------------------------------------------------------------------------
// Kernel 4: out = scaled-P @ V, R8 counted-vmcnt loop with per-ktile scale
// on the A fragments. grid.x=64 (db=x>>4, nb=x&15 for XCD-shared P panels).
// Output fp32 [b][2048][512].
// ---------------------------------------------------------------------------
__global__ __launch_bounds__(256, 2)
void out_kernel(const _Float16* __restrict__ P,
                const _Float16* __restrict__ Vt,
                const float2* __restrict__ ML,
                float* __restrict__ out, int b0)
{
    __shared__ _Float16 a0[128 * 64], a1[128 * 64];
    __shared__ _Float16 b0p[128 * 64], b1p[128 * 64];
    __shared__ float scale_lds[128][17];

    const int tid = threadIdx.x;
    const int db = blockIdx.x >> 4, nb = blockIdx.x & 15, bl = blockIdx.y;
    const int bg = b0 + bl;

    if (tid < 128) {
        const float2* mlrow = ML + ((size_t)bl * 2048 + nb * 128 + tid) * 16;
        float2 ml[16];
        float M = -3.4e38f;
#pragma unroll
        for (int t = 0; t < 16; t++) { ml[t] = mlrow[t]; M = fmaxf(M, ml[t].x); }
        float L = 0.0f;
#pragma unroll
        for (int t = 0; t < 16; t++) L += ml[t].y * exp2f((ml[t].x - M) * LOG2E);
        const float invL = 1.0f / L;
#pragma unroll
        for (int t = 0; t < 16; t++)
            scale_lds[tid][t] = exp2f((ml[t].x - M) * LOG2E) * invL;
    }

    const _Float16* Abase = P  + (size_t)bl * 2048 * 2048 + (size_t)(nb * 128) * 2048;
    const _Float16* Bbase = Vt + (size_t)bg * 512  * 2048 + (size_t)(db * 128) * 2048;

    const int lane = tid & 63;
    const int w = tid >> 6;
    const int wr = w >> 1, wc = w & 1;
    const int lrow = lane & 15, lkg = lane >> 4;

    f32x4 acc[4][4];
#pragma unroll
    for (int i = 0; i < 4; i++)
#pragma unroll
        for (int j = 0; j < 4; j++) acc[i][j] = (f32x4)0.0f;

    __syncthreads();   // scale_lds ready; drains ML loads

    // pipeline prologue
    stage128x64(Abase,      2048, a0,  tid);
    stage128x64(Bbase,      2048, b0p, tid);
    stage128x64(Abase + 64, 2048, a1,  tid);
    stage128x64(Bbase + 64, 2048, b1p, tid);
    asm volatile("s_waitcnt vmcnt(8)" ::: "memory");
    __builtin_amdgcn_s_barrier();
    __builtin_amdgcn_sched_barrier(0);

    for (int t = 0; t < 32; ++t) {
        _Float16* acur = (t & 1) ? a1 : a0;
        _Float16* bcur = (t & 1) ? b1p : b0p;
        const int kt = t >> 1;

        f16x8 af[2][4], bf[2][4];
        float sc[4];
#pragma unroll
        for (int kk = 0; kk < 2; kk++) {
#pragma unroll
            for (int mi = 0; mi < 4; mi++)
                af[kk][mi] = lds_frag(acur, wr * 64 + mi * 16 + lrow, kk * 32 + lkg * 8);
#pragma unroll
            for (int ni = 0; ni < 4; ni++)
                bf[kk][ni] = lds_frag(bcur, wc * 64 + ni * 16 + lrow, kk * 32 + lkg * 8);
        }
#pragma unroll
        for (int mi = 0; mi < 4; mi++)
            sc[mi] = scale_lds[wr * 64 + mi * 16 + lrow][kt];
        asm volatile("s_waitcnt lgkmcnt(0)" ::: "memory");
        __builtin_amdgcn_sched_barrier(0);
        __builtin_amdgcn_s_barrier();

        if (t + 2 < 32) {
            stage128x64(Abase + (size_t)(t + 2) * 64, 2048, acur, tid);
            stage128x64(Bbase + (size_t)(t + 2) * 64, 2048, bcur, tid);
        }
        __builtin_amdgcn_sched_barrier(0);

        __builtin_amdgcn_s_setprio(1);
#pragma unroll
        for (int kk = 0; kk < 2; kk++)
#pragma unroll
            for (int mi = 0; mi < 4; mi++) {
                const f16x8 a = af[kk][mi] * (_Float16)sc[mi];
#pragma unroll
                for (int ni = 0; ni < 4; ni++)
                    acc[mi][ni] = __builtin_amdgcn_mfma_f32_16x16x32_f16(
                        a, bf[kk][ni], acc[mi][ni], 0, 0, 0);
            }
        __builtin_amdgcn_s_setprio(0);

        if (t + 2 < 32) asm volatile("s_waitcnt vmcnt(8)" ::: "memory");
        else            asm volatile("s_waitcnt vmcnt(0)" ::: "memory");
        __builtin_amdgcn_sched_barrier(0);
        __builtin_amdgcn_s_barrier();
        __builtin_amdgcn_sched_barrier(0);
    }

#pragma unroll
    for (int mi = 0; mi < 4; mi++) {
        const int nbase = nb * 128 + wr * 64 + mi * 16 + lkg * 4;
#pragma unroll
        for (int ni = 0; ni < 4; ni++) {
            const int d = db * 128 + wc * 64 + ni * 16 + lrow;
#pragma unroll
            for (int rr = 0; rr < 4; rr++)
                out[((size_t)bg * 2048 + nbase + rr) * 512 + d] = acc[mi][ni][rr];
        }
    }
}

// ---------------------------------------------------------------------------
extern "C" void kernel_launch(void* const* d_in, const int* in_sizes, int n_in,
                              void* d_out, int out_size, void* d_ws, size_t ws_size,
                              hipStream_t stream) {
    const float* x  = (const float*)d_in[0];
    const float* Wq = (const float*)d_in[1];
    const float* Wk = (const float*)d_in[2];
    const float* Wv = (const float*)d_in[3];

    const size_t MB = 1024ull * 1024ull;
    char* ws = (char*)d_ws;
    _Float16* Qf = (_Float16*)ws;                                  // 16 MB
    _Float16* Kf = Qf + (size_t)16384 * 512;                       // 16 MB
    _Float16* Vt = Kf + (size_t)16384 * 512;                       // 16 MB
    _Float16* P  = Vt + (size_t)16384 * 512;                       // chunk * 8 MB
    float*    out = (float*)d_out;

    int chunk;
    if      (ws_size >= 120 * MB) chunk = 8;
    else if (ws_size >= 88  * MB) chunk = 4;
    else if (ws_size >= 70  * MB) chunk = 2;
    else                          chunk = 1;

    float2* ML = (float2*)(P + (size_t)chunk * 2048 * 2048);       // chunk * 256 KB

    // Aliases into the P/ML region (dead until score_kernel runs):
    _Float16* xh = (_Float16*)P;                    // 16 MB
    _Float16* Wt = xh + (size_t)16384 * 512;        // 1.5 MB

    convert_kernel<<<2816, 256, 0, stream>>>(x, Wq, Wk, Wv, xh, Wt);
    proj_kernel<<<dim3(128, 12), 256, 0, stream>>>(xh, Wt, Qf, Kf, Vt);

    for (int b0 = 0; b0 < 8; b0 += chunk) {
        score_kernel<<<dim3(chunk, 16, 16), 256, 0, stream>>>(Qf, Kf, P, ML, b0);
        out_kernel<<<dim3(64, chunk), 256, 0, stream>>>(P, Vt, ML, out, b0);
    }
}

// Round 14
// 132.181 us; speedup vs baseline: 1.0846x; 1.0152x over previous
//
#include <hip/hip_runtime.h>
#include <hip/hip_fp16.h>

typedef _Float16 f16x8 __attribute__((ext_vector_type(8)));
typedef _Float16 f16x4 __attribute__((ext_vector_type(4)));
typedef float    f32x4 __attribute__((ext_vector_type(4)));

#define LOG2E 1.44269504f

// ---------------------------------------------------------------------------
// Staging: 128 rows x 64 halves fp16 tile -> 16 KB linear LDS via
// global_load_lds dwordx4 (4 vmem instrs/thread). Source col pre-swizzled
// (byte ^= (row&7)<<4); readers apply the same XOR (rule #21).
// ---------------------------------------------------------------------------
__device__ __forceinline__ void stage128x64(const _Float16* __restrict__ g, int ld,
                                            void* lds, int tid)
{
    const int r0   = tid >> 3;
    const int colh = ((tid & 7) ^ (r0 & 7)) << 3;
    char* lbase = (char*)lds + (tid >> 6) * 1024;
#pragma unroll
    for (int i = 0; i < 4; i++) {
        const _Float16* src = g + (size_t)(i * 32 + r0) * ld + colh;
        __builtin_amdgcn_global_load_lds(
            (const __attribute__((address_space(1))) void*)src,
            (__attribute__((address_space(3))) void*)(lbase + i * 4096),
            16, 0, 0);
    }
}

__device__ __forceinline__ f16x8 lds_frag(const void* lds, int row, int colh)
{
    const int off = row * 128 + ((colh * 2) ^ ((row & 7) << 4));
    return *(const f16x8*)((const char*)lds + off);
}

// ---------------------------------------------------------------------------
// Counted-vmcnt depth-2 pipelined GEMM loop (T4) — the R8 schedule (best).
// ---------------------------------------------------------------------------
template<int NK>
__device__ __forceinline__ void gemm_loop_cv(const _Float16* __restrict__ A, int lda,
                                             const _Float16* __restrict__ B, int ldb,
                                             _Float16* a0, _Float16* a1,
                                             _Float16* b0, _Float16* b1,
                                             f32x4 acc[4][4], int tid,
                                             int wr, int wc, int lrow, int lkg)
{
    stage128x64(A, lda, a0, tid);
    stage128x64(B, ldb, b0, tid);
    stage128x64(A + 64, lda, a1, tid);
    stage128x64(B + 64, ldb, b1, tid);
    asm volatile("s_waitcnt vmcnt(8)" ::: "memory");   // tile0 landed
    __builtin_amdgcn_s_barrier();
    __builtin_amdgcn_sched_barrier(0);

    for (int t = 0; t < NK; ++t) {
        _Float16* acur = (t & 1) ? a1 : a0;
        _Float16* bcur = (t & 1) ? b1 : b0;

        f16x8 af[2][4], bf[2][4];
#pragma unroll
        for (int kk = 0; kk < 2; kk++) {
#pragma unroll
            for (int mi = 0; mi < 4; mi++)
                af[kk][mi] = lds_frag(acur, wr * 64 + mi * 16 + lrow, kk * 32 + lkg * 8);
#pragma unroll
            for (int ni = 0; ni < 4; ni++)
                bf[kk][ni] = lds_frag(bcur, wc * 64 + ni * 16 + lrow, kk * 32 + lkg * 8);
        }
        asm volatile("s_waitcnt lgkmcnt(0)" ::: "memory");
        __builtin_amdgcn_sched_barrier(0);
        __builtin_amdgcn_s_barrier();

        if (t + 2 < NK) {
            stage128x64(A + (size_t)(t + 2) * 64, lda, acur, tid);
            stage128x64(B + (size_t)(t + 2) * 64, ldb, bcur, tid);
        }
        __builtin_amdgcn_sched_barrier(0);

        __builtin_amdgcn_s_setprio(1);
#pragma unroll
        for (int kk = 0; kk < 2; kk++)
#pragma unroll
            for (int mi = 0; mi < 4; mi++)
#pragma unroll
                for (int ni = 0; ni < 4; ni++)
                    acc[mi][ni] = __builtin_amdgcn_mfma_f32_16x16x32_f16(
                        af[kk][mi], bf[kk][ni], acc[mi][ni], 0, 0, 0);
        __builtin_amdgcn_s_setprio(0);

        if (t + 2 < NK) asm volatile("s_waitcnt vmcnt(8)" ::: "memory");
        else            asm volatile("s_waitcnt vmcnt(0)" ::: "memory");
        __builtin_amdgcn_sched_barrier(0);
        __builtin_amdgcn_s_barrier();
        __builtin_amdgcn_sched_barrier(0);
    }
}

// ---------------------------------------------------------------------------
// Kernel 0: convert x -> fp16 xh; W{q,k,v} -> fp16 transposed Wt[3][n][k].
// ---------------------------------------------------------------------------
__global__ __launch_bounds__(256)
void convert_kernel(const float* __restrict__ x,
                    const float* __restrict__ Wq,
                    const float* __restrict__ Wk,
                    const float* __restrict__ Wv,
                    _Float16* __restrict__ xh,
                    _Float16* __restrict__ Wt)
{
    const int b = blockIdx.x;
    if (b < 2048) {
        const size_t base = (size_t)b * 4096 + (size_t)threadIdx.x * 4;
#pragma unroll
        for (int i = 0; i < 4; i++) {
            f32x4 v = *(const f32x4*)(x + base + i * 1024);
            f16x4 h;
#pragma unroll
            for (int j = 0; j < 4; j++) h[j] = (_Float16)v[j];
            *(f16x4*)(xh + base + i * 1024) = h;
        }
    } else {
        __shared__ float tb[32][33];
        const int t = b - 2048;
        const int mat = t >> 8;
        const int tile = t & 255;
        const int tr = tile >> 4, tc = tile & 15;
        const float* W = (mat == 0) ? Wq : (mat == 1) ? Wk : Wv;
        const int r = threadIdx.x >> 5, c = threadIdx.x & 31;
#pragma unroll
        for (int p = 0; p < 4; p++)
            tb[p * 8 + r][c] = W[(size_t)(tr * 32 + p * 8 + r) * 512 + tc * 32 + c];
        __syncthreads();
#pragma unroll
        for (int p = 0; p < 4; p++)
            Wt[((size_t)mat * 512 + tc * 32 + p * 8 + r) * 512 + tr * 32 + c] =
                (_Float16)tb[c][p * 8 + r];
    }
}

// ---------------------------------------------------------------------------
// Kernel 1: QKV projection (all-fp16). Q,K row-major; V transposed [b][d][m].
// grid (mb=128 x, cb=12 y) for XCD-shared xh panels.
// ---------------------------------------------------------------------------
__global__ __launch_bounds__(256, 2)
void proj_kernel(const _Float16* __restrict__ xh,
                 const _Float16* __restrict__ Wt,
                 _Float16* __restrict__ Qf,
                 _Float16* __restrict__ Kf,
                 _Float16* __restrict__ Vt)
{
    __shared__ _Float16 a0[128 * 64], a1[128 * 64];
    __shared__ _Float16 b0[128 * 64], b1[128 * 64];

    const int tid = threadIdx.x;
    const int mb = blockIdx.x, cb = blockIdx.y;
    const int mat = cb >> 2, nb = cb & 3;
    const int m0 = mb * 128, n0 = nb * 128;

    const _Float16* Abase = xh + (size_t)m0 * 512;
    const _Float16* Bbase = Wt + ((size_t)mat * 512 + n0) * 512;

    const int lane = tid & 63;
    const int w = tid >> 6;
    const int wr = w >> 1, wc = w & 1;
    const int lrow = lane & 15, lkg = lane >> 4;

    f32x4 acc[4][4];
#pragma unroll
    for (int i = 0; i < 4; i++)
#pragma unroll
        for (int j = 0; j < 4; j++) acc[i][j] = (f32x4)0.0f;

    gemm_loop_cv<8>(Abase, 512, Bbase, 512, a0, a1, b0, b1,
                    acc, tid, wr, wc, lrow, lkg);

    if (mat < 2) {
        _Float16* Out = (mat == 0) ? Qf : Kf;
#pragma unroll
        for (int mi = 0; mi < 4; mi++) {
            const int mbase = m0 + wr * 64 + mi * 16 + lkg * 4;
#pragma unroll
            for (int ni = 0; ni < 4; ni++) {
                const int ncol = n0 + wc * 64 + ni * 16 + lrow;
#pragma unroll
                for (int r = 0; r < 4; r++)
                    Out[(size_t)(mbase + r) * 512 + ncol] = (_Float16)acc[mi][ni][r];
            }
        }
    } else {
#pragma unroll
        for (int mi = 0; mi < 4; mi++) {
            const int mglob = m0 + wr * 64 + mi * 16 + lkg * 4;
            const int b = mglob >> 11, mloc = mglob & 2047;
#pragma unroll
            for (int ni = 0; ni < 4; ni++) {
                const int d = n0 + wc * 64 + ni * 16 + lrow;
                f16x4 h;
#pragma unroll
                for (int r = 0; r < 4; r++) h[r] = (_Float16)acc[mi][ni][r];
                *(f16x4*)&Vt[((size_t)b * 512 + d) * 2048 + mloc] = h;
            }
        }
    }
}

// ---------------------------------------------------------------------------
// Kernel 2: S-tile = Q @ K^T (R8 counted-vmcnt loop), LDS-transpose softmax
// epilogue with SEGMENTED column ownership (R11 best epilogue). Grid is
// BATCH-MAJOR: bl=blockIdx.x so linear id mod 8 == bl -> each XCD owns one
// batch; per-XCD working set (Q+K of one batch) = 4 MB ~= L2 capacity.
// ---------------------------------------------------------------------------
__global__ __launch_bounds__(256, 2)
void score_kernel(const _Float16* __restrict__ Qf,
                  const _Float16* __restrict__ Kf,
                  _Float16* __restrict__ P,
                  float2* __restrict__ ML, int b0)
{
    __shared__ __align__(16) char smem[65536];
    _Float16* a0  = (_Float16*)smem;
    _Float16* a1  = (_Float16*)(smem + 16384);
    _Float16* b0p = (_Float16*)(smem + 32768);
    _Float16* b1p = (_Float16*)(smem + 49152);
    float (*S_lds)[132] = (float(*)[132])smem;     // 33792 B, aliases buffers

    const int tid = threadIdx.x;
    const int bl = blockIdx.x, mb = blockIdx.y, nb = blockIdx.z;
    const int bg = b0 + bl;

    const _Float16* Abase = Qf + (size_t)(bg * 2048 + nb * 128) * 512;
    const _Float16* Bbase = Kf + (size_t)(bg * 2048 + mb * 128) * 512;

    const int lane = tid & 63;
    const int w = tid >> 6;
    const int wr = w >> 1, wc = w & 1;
    const int lrow = lane & 15, lkg = lane >> 4;

    f32x4 acc[4][4];
#pragma unroll
    for (int i = 0; i < 4; i++)
#pragma unroll
        for (int j = 0; j < 4; j++) acc[i][j] = (f32x4)0.0f;

    gemm_loop_cv<8>(Abase, 512, Bbase, 512, a0, a1, b0p, b1p,
                    acc, tid, wr, wc, lrow, lkg);
    // final s_barrier: all waves' frags in regs -> S_lds reuse safe

    _Float16* Pb = P + (size_t)bl * 2048 * 2048;
    const int s  = tid >> 2;          // 0..63: S_lds row this thread reduces
    const int q4 = tid & 3;           // 8-col segment selector

#pragma unroll
    for (int hp = 0; hp < 2; hp++) {
        // ---- scatter this half's acc quadrants into S_lds ----
#pragma unroll
        for (int m2 = 0; m2 < 2; m2++) {
            const int mi = hp * 2 + m2;
            const int srow = wr * 32 + m2 * 16 + lkg * 4;
#pragma unroll
            for (int ni = 0; ni < 4; ni++) {
                const int col = wc * 64 + ni * 16 + lrow;
#pragma unroll
                for (int rr = 0; rr < 4; rr++)
                    S_lds[srow + rr][col] = acc[mi][ni][rr];
            }
        }
        __syncthreads();

        // ---- segmented re-read: thread owns 4 x 8-col runs at 32 stride ----
        f32x4 vv[8];
#pragma unroll
        for (int seg = 0; seg < 4; seg++) {
            vv[seg * 2 + 0] = *(const f32x4*)&S_lds[s][q4 * 8 + seg * 32 + 0];
            vv[seg * 2 + 1] = *(const f32x4*)&S_lds[s][q4 * 8 + seg * 32 + 4];
        }

        float m = vv[0][0];
#pragma unroll
        for (int j = 0; j < 8; j++)
#pragma unroll
            for (int jj = 0; jj < 4; jj++) m = fmaxf(m, vv[j][jj]);
        m = fmaxf(m, __shfl_xor(m, 1));
        m = fmaxf(m, __shfl_xor(m, 2));

        float l = 0.0f;
#pragma unroll
        for (int j = 0; j < 8; j++)
#pragma unroll
            for (int jj = 0; jj < 4; jj++) {
                float e = exp2f((vv[j][jj] - m) * LOG2E);
                vv[j][jj] = e;
                l += e;
            }
        l += __shfl_xor(l, 1);
        l += __shfl_xor(l, 2);

        const int q_local = (s >> 5) * 64 + hp * 32 + (s & 31);
        const int q = nb * 128 + q_local;

        if (q4 == 0) {
            float2 v; v.x = m; v.y = l;
            ML[((size_t)bl * 2048 + q) * 16 + mb] = v;
        }

        // ---- pack fp16: per seg, lanes 0-3 write dense 64 B ----
#pragma unroll
        for (int seg = 0; seg < 4; seg++) {
            f16x8 h;
#pragma unroll
            for (int jj = 0; jj < 4; jj++) {
                h[jj]     = (_Float16)vv[seg * 2 + 0][jj];
                h[jj + 4] = (_Float16)vv[seg * 2 + 1][jj];
            }
            *(f16x8*)&Pb[(size_t)q * 2048 + mb * 128 + q4 * 8 + seg * 32] = h;
        }
        __syncthreads();   // S_lds reads done before next half overwrites
    }
}

// ---------------------------------------------------------------------------
// Kernel 4: out = scaled-P @ V, R8 counted-vmcnt loop with per-ktile scale
// on the A fragments. BATCH-MAJOR grid (chunk, 64): bl=blockIdx.x so each
// XCD owns one batch (P 8MB + V 2MB working set); P-panel db-sharers and
// V-panel nb-sharers both stay same-XCD. Output fp32 [b][2048][512].
// ---------------------------------------------------------------------------
__global__ __launch_bounds__(256, 2)
void out_kernel(const _Float16* __restrict__ P,
                const _Float16* __restrict__ Vt,
                const float2* __restrict__ ML,
                float* __restrict__ out, int b0)
{
    __shared__ _Float16 a0[128 * 64], a1[128 * 64];
    __shared__ _Float16 b0p[128 * 64], b1p[128 * 64];
    __shared__ float scale_lds[128][17];

    const int tid = threadIdx.x;
    const int bl = blockIdx.x;
    const int db = blockIdx.y >> 4, nb = blockIdx.y & 15;
    const int bg = b0 + bl;

    if (tid < 128) {
        const float2* mlrow = ML + ((size_t)bl * 2048 + nb * 128 + tid) * 16;
        float2 ml[16];
        float M = -3.4e38f;
#pragma unroll
        for (int t = 0; t < 16; t++) { ml[t] = mlrow[t]; M = fmaxf(M, ml[t].x); }
        float L = 0.0f;
#pragma unroll
        for (int t = 0; t < 16; t++) L += ml[t].y * exp2f((ml[t].x - M) * LOG2E);
        const float invL = 1.0f / L;
#pragma unroll
        for (int t = 0; t < 16; t++)
            scale_lds[tid][t] = exp2f((ml[t].x - M) * LOG2E) * invL;
    }

    const _Float16* Abase = P  + (size_t)bl * 2048 * 2048 + (size_t)(nb * 128) * 2048;
    const _Float16* Bbase = Vt + (size_t)bg * 512  * 2048 + (size_t)(db * 128) * 2048;

    const int lane = tid & 63;
    const int w = tid >> 6;
    const int wr = w >> 1, wc = w & 1;
    const int lrow = lane & 15, lkg = lane >> 4;

    f32x4 acc[4][4];
#pragma unroll
    for (int i = 0; i < 4; i++)
#pragma unroll
        for (int j = 0; j < 4; j++) acc[i][j] = (f32x4)0.0f;

    __syncthreads();   // scale_lds ready; drains ML loads

    // pipeline prologue
    stage128x64(Abase,      2048, a0,  tid);
    stage128x64(Bbase,      2048, b0p, tid);
    stage128x64(Abase + 64, 2048, a1,  tid);
    stage128x64(Bbase + 64, 2048, b1p, tid);
    asm volatile("s_waitcnt vmcnt(8)" ::: "memory");
    __builtin_amdgcn_s_barrier();
    __builtin_amdgcn_sched_barrier(0);

    for (int t = 0; t < 32; ++t) {
        _Float16* acur = (t & 1) ? a1 : a0;
        _Float16* bcur = (t & 1) ? b1p : b0p;
        const int kt = t >> 1;

        f16x8 af[2][4], bf[2][4];
        float sc[4];
#pragma unroll
        for (int kk = 0; kk < 2; kk++) {
#pragma unroll
            for (int mi = 0; mi < 4; mi++)
                af[kk][mi] = lds_frag(acur, wr * 64 + mi * 16 + lrow, kk * 32 + lkg * 8);
#pragma unroll
            for (int ni = 0; ni < 4; ni++)
                bf[kk][ni] = lds_frag(bcur, wc * 64 + ni * 16 + lrow, kk * 32 + lkg * 8);
        }
#pragma unroll
        for (int mi = 0; mi < 4; mi++)
            sc[mi] = scale_lds[wr * 64 + mi * 16 + lrow][kt];
        asm volatile("s_waitcnt lgkmcnt(0)" ::: "memory");
        __builtin_amdgcn_sched_barrier(0);
        __builtin_amdgcn_s_barrier();

        if (t + 2 < 32) {
            stage128x64(Abase + (size_t)(t + 2) * 64, 2048, acur, tid);
            stage128x64(Bbase + (size_t)(t + 2) * 64, 2048, bcur, tid);
        }
        __builtin_amdgcn_sched_barrier(0);

        __builtin_amdgcn_s_setprio(1);
#pragma unroll
        for (int kk = 0; kk < 2; kk++)
#pragma unroll
            for (int mi = 0; mi < 4; mi++) {
                const f16x8 a = af[kk][mi] * (_Float16)sc[mi];
#pragma unroll
                for (int ni = 0; ni < 4; ni++)
                    acc[mi][ni] = __builtin_amdgcn_mfma_f32_16x16x32_f16(
                        a, bf[kk][ni], acc[mi][ni], 0, 0, 0);
            }
        __builtin_amdgcn_s_setprio(0);

        if (t + 2 < 32) asm volatile("s_waitcnt vmcnt(8)" ::: "memory");
        else            asm volatile("s_waitcnt vmcnt(0)" ::: "memory");
        __builtin_amdgcn_sched_barrier(0);
        __builtin_amdgcn_s_barrier();
        __builtin_amdgcn_sched_barrier(0);
    }

#pragma unroll
    for (int mi = 0; mi < 4; mi++) {
        const int nbase = nb * 128 + wr * 64 + mi * 16 + lkg * 4;
#pragma unroll
        for (int ni = 0; ni < 4; ni++) {
            const int d = db * 128 + wc * 64 + ni * 16 + lrow;
#pragma unroll
            for (int rr = 0; rr < 4; rr++)
                out[((size_t)bg * 2048 + nbase + rr) * 512 + d] = acc[mi][ni][rr];
        }
    }
}

// ---------------------------------------------------------------------------
extern "C" void kernel_launch(void* const* d_in, const int* in_sizes, int n_in,
                              void* d_out, int out_size, void* d_ws, size_t ws_size,
                              hipStream_t stream) {
    const float* x  = (const float*)d_in[0];
    const float* Wq = (const float*)d_in[1];
    const float* Wk = (const float*)d_in[2];
    const float* Wv = (const float*)d_in[3];

    const size_t MB = 1024ull * 1024ull;
    char* ws = (char*)d_ws;
    _Float16* Qf = (_Float16*)ws;                                  // 16 MB
    _Float16* Kf = Qf + (size_t)16384 * 512;                       // 16 MB
    _Float16* Vt = Kf + (size_t)16384 * 512;                       // 16 MB
    _Float16* P  = Vt + (size_t)16384 * 512;                       // chunk * 8 MB
    float*    out = (float*)d_out;

    int chunk;
    if      (ws_size >= 120 * MB) chunk = 8;
    else if (ws_size >= 88  * MB) chunk = 4;
    else if (ws_size >= 70  * MB) chunk = 2;
    else                          chunk = 1;

    float2* ML = (float2*)(P + (size_t)chunk * 2048 * 2048);       // chunk * 256 KB

    // Aliases into the P/ML region (dead until score_kernel runs):
    _Float16* xh = (_Float16*)P;                    // 16 MB
    _Float16* Wt = xh + (size_t)16384 * 512;        // 1.5 MB

    convert_kernel<<<2816, 256, 0, stream>>>(x, Wq, Wk, Wv, xh, Wt);
    proj_kernel<<<dim3(128, 12), 256, 0, stream>>>(xh, Wt, Qf, Kf, Vt);

    for (int b0 = 0; b0 < 8; b0 += chunk) {
        score_kernel<<<dim3(chunk, 16, 16), 256, 0, stream>>>(Qf, Kf, P, ML, b0);
        out_kernel<<<dim3(chunk, 64), 256, 0, stream>>>(P, Vt, ML, out, b0);
    }
}